// Round 2
// baseline (12524.828 us; speedup 1.0000x reference)
//
#include <hip/hip_runtime.h>
#include <math.h>

// Problem dims (fixed by reference)
//  B=1024, T=128, I=128, H=256, 3H=768, K=8, E1=512, E2=256, C=2

// ---------------------------------------------------------------------------
// fp32 GEMM, 128x128 tile, 256 threads, 8x8 per-thread microtile.
// C[m, z, n] = act( sum_k Arow(m,z)[k] * W[z][n][k] + b[z][n] )
// A row address = A + (m>>10)*a_sT + (m&1023)*a_sB + z*a_sZ (row of K floats)
// M % 128 == 0, N % 128 == 0, K % 16 == 0.
// LDS-balance: 64 B LDS-read per 64 FMA per thread per kk = 1.0 B/FMA.
// b-fragment split tx*4 / 64+tx*4 -> LDS read banks 2-way max (free).
// ---------------------------------------------------------------------------
template<int ACT>
__global__ __launch_bounds__(256)
void gemm_f32(const float* __restrict__ A, const float* __restrict__ W,
              const float* __restrict__ bias, float* __restrict__ C,
              int K,
              long a_sT, long a_sB, long a_sZ,
              long w_sZ, long b_sZ, long c_row, long c_sZ)
{
  __shared__ alignas(16) float As[16][132];
  __shared__ alignas(16) float Ws[16][132];
  const int z = blockIdx.z;
  const float* Az = A + (long)z * a_sZ;
  const float* Wz = W + (long)z * w_sZ;
  const float* bz = bias + (long)z * b_sZ;
  const int m0 = blockIdx.y * 128;
  const int n0 = blockIdx.x * 128;
  const int tid = threadIdx.x;
  const int tx = tid & 15, ty = tid >> 4;

  // staging indices: idx = tid + p*256; row = idx>>2 (0..127), kq = idx&3
  const int row0 = tid >> 2, kq0 = tid & 3;
  const int row1 = (tid + 256) >> 2, kq1 = kq0;   // +256 -> row+64, same kq

  float acc[8][8];
  #pragma unroll
  for (int i = 0; i < 8; ++i)
    #pragma unroll
    for (int j = 0; j < 8; ++j) acc[i][j] = 0.f;

  // A/W row base pointers for the two staged float4s each
  const int ma0 = m0 + row0, ma1 = m0 + row1;
  const float* apr0 = Az + (long)(ma0 >> 10) * a_sT + (long)(ma0 & 1023) * a_sB + kq0 * 4;
  const float* apr1 = Az + (long)(ma1 >> 10) * a_sT + (long)(ma1 & 1023) * a_sB + kq1 * 4;
  const float* wpr0 = Wz + (long)(n0 + row0) * K + kq0 * 4;
  const float* wpr1 = Wz + (long)(n0 + row1) * K + kq1 * 4;

  float4 pa0 = *(const float4*)(apr0);
  float4 pa1 = *(const float4*)(apr1);
  float4 pw0 = *(const float4*)(wpr0);
  float4 pw1 = *(const float4*)(wpr1);

  for (int k0 = 0; k0 < K; k0 += 16) {
    // store staged regs -> LDS (transpose to [k][m]/[k][n])
    As[kq0*4+0][row0] = pa0.x; As[kq0*4+1][row0] = pa0.y;
    As[kq0*4+2][row0] = pa0.z; As[kq0*4+3][row0] = pa0.w;
    As[kq1*4+0][row1] = pa1.x; As[kq1*4+1][row1] = pa1.y;
    As[kq1*4+2][row1] = pa1.z; As[kq1*4+3][row1] = pa1.w;
    Ws[kq0*4+0][row0] = pw0.x; Ws[kq0*4+1][row0] = pw0.y;
    Ws[kq0*4+2][row0] = pw0.z; Ws[kq0*4+3][row0] = pw0.w;
    Ws[kq1*4+0][row1] = pw1.x; Ws[kq1*4+1][row1] = pw1.y;
    Ws[kq1*4+2][row1] = pw1.z; Ws[kq1*4+3][row1] = pw1.w;
    __syncthreads();

    if (k0 + 16 < K) {   // prefetch next k-tile while computing this one
      pa0 = *(const float4*)(apr0 + k0 + 16);
      pa1 = *(const float4*)(apr1 + k0 + 16);
      pw0 = *(const float4*)(wpr0 + k0 + 16);
      pw1 = *(const float4*)(wpr1 + k0 + 16);
    }

    #pragma unroll
    for (int kk = 0; kk < 16; ++kk) {
      float4 a0 = *(const float4*)&As[kk][ty * 8];
      float4 a1 = *(const float4*)&As[kk][ty * 8 + 4];
      float4 b0 = *(const float4*)&Ws[kk][tx * 4];
      float4 b1 = *(const float4*)&Ws[kk][64 + tx * 4];
      float a[8] = {a0.x,a0.y,a0.z,a0.w,a1.x,a1.y,a1.z,a1.w};
      float b[8] = {b0.x,b0.y,b0.z,b0.w,b1.x,b1.y,b1.z,b1.w};
      #pragma unroll
      for (int i = 0; i < 8; ++i)
        #pragma unroll
        for (int j = 0; j < 8; ++j)
          acc[i][j] = fmaf(a[i], b[j], acc[i][j]);
    }
    __syncthreads();
  }

  float4 bv0 = *(const float4*)&bz[n0 + tx * 4];
  float4 bv1 = *(const float4*)&bz[n0 + 64 + tx * 4];
  #pragma unroll
  for (int i = 0; i < 8; ++i) {
    int m = m0 + ty * 8 + i;
    float* cp = C + (long)m * c_row + (long)z * c_sZ + n0;
    float4 o0, o1;
    o0.x = acc[i][0] + bv0.x; o0.y = acc[i][1] + bv0.y;
    o0.z = acc[i][2] + bv0.z; o0.w = acc[i][3] + bv0.w;
    o1.x = acc[i][4] + bv1.x; o1.y = acc[i][5] + bv1.y;
    o1.z = acc[i][6] + bv1.z; o1.w = acc[i][7] + bv1.w;
    if (ACT == 1) {
      o0.x = fmaxf(o0.x, 0.f); o0.y = fmaxf(o0.y, 0.f);
      o0.z = fmaxf(o0.z, 0.f); o0.w = fmaxf(o0.w, 0.f);
      o1.x = fmaxf(o1.x, 0.f); o1.y = fmaxf(o1.y, 0.f);
      o1.z = fmaxf(o1.z, 0.f); o1.w = fmaxf(o1.w, 0.f);
    }
    *(float4*)(cp + tx * 4) = o0;
    *(float4*)(cp + 64 + tx * 4) = o1;
  }
}

// ---------------------------------------------------------------------------
// GRU recurrence over Tc steps. One block = 8 batch rows, 512 threads.
// Two 256-thread halves process different rows but issue IDENTICAL W_hh
// addresses in lockstep -> second request L1-hits, halving L2 traffic.
// Thread (g, d): g = tid>>8 picks row group, d = tid&255 owns hidden dim d.
// ---------------------------------------------------------------------------
__global__ __launch_bounds__(512)
void gru_rec(const float* __restrict__ gi, const float* __restrict__ Whh,
             const float* __restrict__ b_hh, float* __restrict__ h_state,
             float* __restrict__ h_out, int Tc, int store_all)
{
  __shared__ alignas(16) float hs[8][256];
  const int tid = threadIdx.x;
  const int d = tid & 255;
  const int g = tid >> 8;                 // 0 or 1
  const int b0 = blockIdx.x * 8 + g * 4;  // this half's 4 batch rows
  float* hrow[4];
  #pragma unroll
  for (int r = 0; r < 4; ++r) {
    hs[g * 4 + r][d] = h_state[(long)(b0 + r) * 256 + d];
  }
  __syncthreads();

  const float bhr = b_hh[d];
  const float bhz = b_hh[256 + d];
  const float bhn = b_hh[512 + d];
  const float4* Wr = (const float4*)(Whh + (long)d * 256);
  const float4* Wz = (const float4*)(Whh + (long)(256 + d) * 256);
  const float4* Wn = (const float4*)(Whh + (long)(512 + d) * 256);

  for (int t = 0; t < Tc; ++t) {
    float ar[4] = {0,0,0,0}, az[4] = {0,0,0,0}, an[4] = {0,0,0,0};
    for (int k4 = 0; k4 < 64; ++k4) {
      float4 wr = Wr[k4], wz = Wz[k4], wn = Wn[k4];
      #pragma unroll
      for (int r = 0; r < 4; ++r) {
        float4 hv = *(const float4*)&hs[g * 4 + r][k4 * 4];   // LDS broadcast
        ar[r] = fmaf(hv.x, wr.x, ar[r]); ar[r] = fmaf(hv.y, wr.y, ar[r]);
        ar[r] = fmaf(hv.z, wr.z, ar[r]); ar[r] = fmaf(hv.w, wr.w, ar[r]);
        az[r] = fmaf(hv.x, wz.x, az[r]); az[r] = fmaf(hv.y, wz.y, az[r]);
        az[r] = fmaf(hv.z, wz.z, az[r]); az[r] = fmaf(hv.w, wz.w, az[r]);
        an[r] = fmaf(hv.x, wn.x, an[r]); an[r] = fmaf(hv.y, wn.y, an[r]);
        an[r] = fmaf(hv.z, wn.z, an[r]); an[r] = fmaf(hv.w, wn.w, an[r]);
      }
    }
    float hnew[4];
    #pragma unroll
    for (int r = 0; r < 4; ++r) {
      const float* gip = gi + ((long)t * 1024 + b0 + r) * 768;
      float ir  = gip[d];
      float iz  = gip[256 + d];
      float in_ = gip[512 + d];
      float rg = 1.f / (1.f + __expf(-(ir + ar[r] + bhr)));
      float zg = 1.f / (1.f + __expf(-(iz + az[r] + bhz)));
      float ng = tanhf(in_ + rg * (an[r] + bhn));
      hnew[r] = (1.f - zg) * ng + zg * hs[g * 4 + r][d];
    }
    __syncthreads();   // all k-loops done reading hs before overwrite
    #pragma unroll
    for (int r = 0; r < 4; ++r) {
      hs[g * 4 + r][d] = hnew[r];
      if (store_all)
        h_out[((long)t * 1024 + b0 + r) * 256 + d] = hnew[r];
    }
    __syncthreads();
  }
  #pragma unroll
  for (int r = 0; r < 4; ++r)
    h_state[(long)(b0 + r) * 256 + d] = hs[g * 4 + r][d];
}

// ---------------------------------------------------------------------------
// Soft cluster assignment: q[b,k] ∝ 1/(1+||z_b - c_k||²)  (alpha=1), normalized.
// ---------------------------------------------------------------------------
__global__ __launch_bounds__(64)
void cluster_q(const float* __restrict__ zlat, const float* __restrict__ centers,
               float* __restrict__ q)
{
  __shared__ float red[64];
  __shared__ float qv[8];
  const int b = blockIdx.x;
  const int tid = threadIdx.x;
  const int k = tid >> 3, p = tid & 7;
  const float4* zp = (const float4*)(zlat + (long)b * 256 + p * 32);
  const float4* cp = (const float4*)(centers + (long)k * 256 + p * 32);
  float s = 0.f;
  #pragma unroll
  for (int i = 0; i < 8; ++i) {
    float4 zv = zp[i], cv = cp[i];
    float dx = zv.x - cv.x, dy = zv.y - cv.y;
    float dz = zv.z - cv.z, dw = zv.w - cv.w;
    s += dx*dx + dy*dy + dz*dz + dw*dw;
  }
  red[tid] = s;
  __syncthreads();
  if (tid < 8) {
    float d2 = 0.f;
    #pragma unroll
    for (int p2 = 0; p2 < 8; ++p2) d2 += red[tid * 8 + p2];
    qv[tid] = 1.f / (1.f + d2);
  }
  __syncthreads();
  if (tid < 8) {
    float ssum = 0.f;
    #pragma unroll
    for (int kk = 0; kk < 8; ++kk) ssum += qv[kk];
    q[(long)b * 8 + tid] = qv[tid] / ssum;
  }
}

// ---------------------------------------------------------------------------
// logits[b,k,c] = h2[b,k,:]·eW3[k,c,:] + eb3[k,c]; preds[b,c] = Σ_k q[b,k]*logits
// ---------------------------------------------------------------------------
__global__ __launch_bounds__(256)
void combine_preds(const float* __restrict__ h2, const float* __restrict__ eW3,
                   const float* __restrict__ eb3, const float* __restrict__ q,
                   float* __restrict__ out)
{
  __shared__ float p0[256], p1[256];
  __shared__ float lc[16];
  const int b = blockIdx.x;
  const int tid = threadIdx.x;
  const int k = tid >> 5, w = tid & 31;
  const float* h2p = h2 + (long)b * (8 * 256) + (long)k * 256 + w * 8;
  const float* w0  = eW3 + (long)k * 512 + w * 8;          // c=0
  const float* w1  = eW3 + (long)k * 512 + 256 + w * 8;    // c=1
  float c0 = 0.f, c1 = 0.f;
  #pragma unroll
  for (int i = 0; i < 8; ++i) {
    float hv = h2p[i];
    c0 = fmaf(hv, w0[i], c0);
    c1 = fmaf(hv, w1[i], c1);
  }
  p0[tid] = c0; p1[tid] = c1;
  __syncthreads();
  if (tid < 16) {
    int kk = tid >> 1, c = tid & 1;
    const float* pp = (c == 0) ? p0 : p1;
    float s = 0.f;
    for (int w2 = 0; w2 < 32; ++w2) s += pp[kk * 32 + w2];
    s += eb3[kk * 2 + c];
    lc[tid] = q[(long)b * 8 + kk] * s;
  }
  __syncthreads();
  if (tid < 2) {
    float s = 0.f;
    #pragma unroll
    for (int kk = 0; kk < 8; ++kk) s += lc[kk * 2 + tid];
    out[(long)b * 2 + tid] = s;
  }
}

// Zero-fill helper (avoid relying on memset semantics under graph capture)
__global__ __launch_bounds__(256)
void zero_fill(float* __restrict__ p, long n)
{
  long i = (long)blockIdx.x * 256 + threadIdx.x;
  if (i < n) p[i] = 0.f;
}

// ---------------------------------------------------------------------------
extern "C" void kernel_launch(void* const* d_in, const int* in_sizes, int n_in,
                              void* d_out, int out_size, void* d_ws, size_t ws_size,
                              hipStream_t stream)
{
  const float* x       = (const float*)d_in[0];
  const float* W_ih0   = (const float*)d_in[1];
  const float* W_hh0   = (const float*)d_in[2];
  const float* b_ih0   = (const float*)d_in[3];
  const float* b_hh0   = (const float*)d_in[4];
  const float* W_ih1   = (const float*)d_in[5];
  const float* W_hh1   = (const float*)d_in[6];
  const float* b_ih1   = (const float*)d_in[7];
  const float* b_hh1   = (const float*)d_in[8];
  const float* centers = (const float*)d_in[9];
  const float* eW1     = (const float*)d_in[10];
  const float* eb1     = (const float*)d_in[11];
  const float* eW2     = (const float*)d_in[12];
  const float* eb2     = (const float*)d_in[13];
  const float* eW3     = (const float*)d_in[14];
  const float* eb3     = (const float*)d_in[15];
  float* out = (float*)d_out;
  (void)in_sizes; (void)n_in; (void)out_size;

  // ---- workspace layout ----
  char* base = (char*)d_ws;
  size_t off = 0;
  auto alloc = [&](size_t nbytes) -> void* {
    void* p = base + off;
    off += (nbytes + 255) & ~(size_t)255;
    return p;
  };
  float* h0_state = (float*)alloc(1024ull * 256 * 4);
  float* h1_state = (float*)alloc(1024ull * 256 * 4);   // == z after layer 1
  float* qbuf     = (float*)alloc(1024ull * 8 * 4);
  float* h1buf    = (float*)alloc(1024ull * 8 * 512 * 4);
  float* h2buf    = (float*)alloc(1024ull * 8 * 256 * 4);
  const size_t fixed = off;

  // largest T-chunk that fits ws_size (deterministic given ws_size)
  int Tc = 1;
  const int cands[7] = {128, 64, 32, 16, 8, 4, 2};
  for (int ci = 0; ci < 7; ++ci) {
    size_t need = fixed + (size_t)cands[ci] * 1024 * (768 + 768 + 256) * 4 + 1024;
    if (need <= ws_size) { Tc = cands[ci]; break; }
  }
  float* gi0 = (float*)alloc((size_t)Tc * 1024 * 768 * 4);
  float* gi1 = (float*)alloc((size_t)Tc * 1024 * 768 * 4);
  float* h0c = (float*)alloc((size_t)Tc * 1024 * 256 * 4);

  // ---- zero recurrent states (ws is poisoned 0xAA before every call) ----
  {
    long n = 2L * 1024 * 256;   // h0_state + h1_state are contiguous
    zero_fill<<<dim3((unsigned)((n + 255) / 256)), 256, 0, stream>>>(h0_state, n);
  }

  // ---- 2-layer GRU, chunked over time ----
  for (int t0 = 0; t0 < 128; t0 += Tc) {
    // gi0[tl,b,:] = x[b, t0+tl, :] @ W_ih0^T + b_ih0
    gemm_f32<0><<<dim3(6, Tc * 8, 1), 256, 0, stream>>>(
        x + (long)t0 * 128, W_ih0, b_ih0, gi0, 128,
        /*a_sT*/ 128, /*a_sB*/ 128L * 128, /*a_sZ*/ 0,
        /*w_sZ*/ 0, /*b_sZ*/ 0, /*c_row*/ 768, /*c_sZ*/ 0);
    gru_rec<<<128, 512, 0, stream>>>(gi0, W_hh0, b_hh0, h0_state, h0c, Tc, 1);

    // gi1[tl,b,:] = h0c[tl,b,:] @ W_ih1^T + b_ih1
    gemm_f32<0><<<dim3(6, Tc * 8, 1), 256, 0, stream>>>(
        h0c, W_ih1, b_ih1, gi1, 256,
        /*a_sT*/ 1024L * 256, /*a_sB*/ 256, /*a_sZ*/ 0,
        /*w_sZ*/ 0, /*b_sZ*/ 0, /*c_row*/ 768, /*c_sZ*/ 0);
    gru_rec<<<128, 512, 0, stream>>>(gi1, W_hh1, b_hh1, h1_state, nullptr, Tc, 0);
  }

  // ---- soft cluster assignment ----
  cluster_q<<<1024, 64, 0, stream>>>(h1_state, centers, qbuf);

  // ---- experts: h1 = relu(z @ eW1[k]^T + eb1[k]) ----
  gemm_f32<1><<<dim3(4, 8, 8), 256, 0, stream>>>(
      h1_state, eW1, eb1, h1buf, 256,
      /*a_sT*/ 0, /*a_sB*/ 256, /*a_sZ*/ 0,
      /*w_sZ*/ 512L * 256, /*b_sZ*/ 512, /*c_row*/ 8L * 512, /*c_sZ*/ 512);
  // h2 = relu(h1 @ eW2[k]^T + eb2[k])
  gemm_f32<1><<<dim3(2, 8, 8), 256, 0, stream>>>(
      h1buf, eW2, eb2, h2buf, 512,
      /*a_sT*/ 0, /*a_sB*/ 8L * 512, /*a_sZ*/ 512,
      /*w_sZ*/ 256L * 512, /*b_sZ*/ 256, /*c_row*/ 8L * 256, /*c_sZ*/ 256);

  // ---- logits + q-weighted combine ----
  combine_preds<<<1024, 256, 0, stream>>>(h2buf, eW3, eb3, qbuf, out);
}

// Round 3
// 4483.535 us; speedup vs baseline: 2.7935x; 2.7935x over previous
//
#include <hip/hip_runtime.h>
#include <math.h>

// Problem dims (fixed by reference)
//  B=1024, T=128, I=128, H=256, 3H=768, K=8, E1=512, E2=256, C=2

// ---------------------------------------------------------------------------
// fp32 GEMM, 128x128 tile, 256 threads, 8x8 per-thread microtile.
// (unchanged from round 2 — "rest" time dropped 1.2ms -> 0.6ms with this)
// ---------------------------------------------------------------------------
template<int ACT>
__global__ __launch_bounds__(256)
void gemm_f32(const float* __restrict__ A, const float* __restrict__ W,
              const float* __restrict__ bias, float* __restrict__ C,
              int K,
              long a_sT, long a_sB, long a_sZ,
              long w_sZ, long b_sZ, long c_row, long c_sZ)
{
  __shared__ alignas(16) float As[16][132];
  __shared__ alignas(16) float Ws[16][132];
  const int z = blockIdx.z;
  const float* Az = A + (long)z * a_sZ;
  const float* Wz = W + (long)z * w_sZ;
  const float* bz = bias + (long)z * b_sZ;
  const int m0 = blockIdx.y * 128;
  const int n0 = blockIdx.x * 128;
  const int tid = threadIdx.x;
  const int tx = tid & 15, ty = tid >> 4;

  const int row0 = tid >> 2, kq0 = tid & 3;
  const int row1 = (tid + 256) >> 2, kq1 = kq0;

  float acc[8][8];
  #pragma unroll
  for (int i = 0; i < 8; ++i)
    #pragma unroll
    for (int j = 0; j < 8; ++j) acc[i][j] = 0.f;

  const int ma0 = m0 + row0, ma1 = m0 + row1;
  const float* apr0 = Az + (long)(ma0 >> 10) * a_sT + (long)(ma0 & 1023) * a_sB + kq0 * 4;
  const float* apr1 = Az + (long)(ma1 >> 10) * a_sT + (long)(ma1 & 1023) * a_sB + kq1 * 4;
  const float* wpr0 = Wz + (long)(n0 + row0) * K + kq0 * 4;
  const float* wpr1 = Wz + (long)(n0 + row1) * K + kq1 * 4;

  float4 pa0 = *(const float4*)(apr0);
  float4 pa1 = *(const float4*)(apr1);
  float4 pw0 = *(const float4*)(wpr0);
  float4 pw1 = *(const float4*)(wpr1);

  for (int k0 = 0; k0 < K; k0 += 16) {
    As[kq0*4+0][row0] = pa0.x; As[kq0*4+1][row0] = pa0.y;
    As[kq0*4+2][row0] = pa0.z; As[kq0*4+3][row0] = pa0.w;
    As[kq1*4+0][row1] = pa1.x; As[kq1*4+1][row1] = pa1.y;
    As[kq1*4+2][row1] = pa1.z; As[kq1*4+3][row1] = pa1.w;
    Ws[kq0*4+0][row0] = pw0.x; Ws[kq0*4+1][row0] = pw0.y;
    Ws[kq0*4+2][row0] = pw0.z; Ws[kq0*4+3][row0] = pw0.w;
    Ws[kq1*4+0][row1] = pw1.x; Ws[kq1*4+1][row1] = pw1.y;
    Ws[kq1*4+2][row1] = pw1.z; Ws[kq1*4+3][row1] = pw1.w;
    __syncthreads();

    if (k0 + 16 < K) {
      pa0 = *(const float4*)(apr0 + k0 + 16);
      pa1 = *(const float4*)(apr1 + k0 + 16);
      pw0 = *(const float4*)(wpr0 + k0 + 16);
      pw1 = *(const float4*)(wpr1 + k0 + 16);
    }

    #pragma unroll
    for (int kk = 0; kk < 16; ++kk) {
      float4 a0 = *(const float4*)&As[kk][ty * 8];
      float4 a1 = *(const float4*)&As[kk][ty * 8 + 4];
      float4 b0 = *(const float4*)&Ws[kk][tx * 4];
      float4 b1 = *(const float4*)&Ws[kk][64 + tx * 4];
      float a[8] = {a0.x,a0.y,a0.z,a0.w,a1.x,a1.y,a1.z,a1.w};
      float b[8] = {b0.x,b0.y,b0.z,b0.w,b1.x,b1.y,b1.z,b1.w};
      #pragma unroll
      for (int i = 0; i < 8; ++i)
        #pragma unroll
        for (int j = 0; j < 8; ++j)
          acc[i][j] = fmaf(a[i], b[j], acc[i][j]);
    }
    __syncthreads();
  }

  float4 bv0 = *(const float4*)&bz[n0 + tx * 4];
  float4 bv1 = *(const float4*)&bz[n0 + 64 + tx * 4];
  #pragma unroll
  for (int i = 0; i < 8; ++i) {
    int m = m0 + ty * 8 + i;
    float* cp = C + (long)m * c_row + (long)z * c_sZ + n0;
    float4 o0, o1;
    o0.x = acc[i][0] + bv0.x; o0.y = acc[i][1] + bv0.y;
    o0.z = acc[i][2] + bv0.z; o0.w = acc[i][3] + bv0.w;
    o1.x = acc[i][4] + bv1.x; o1.y = acc[i][5] + bv1.y;
    o1.z = acc[i][6] + bv1.z; o1.w = acc[i][7] + bv1.w;
    if (ACT == 1) {
      o0.x = fmaxf(o0.x, 0.f); o0.y = fmaxf(o0.y, 0.f);
      o0.z = fmaxf(o0.z, 0.f); o0.w = fmaxf(o0.w, 0.f);
      o1.x = fmaxf(o1.x, 0.f); o1.y = fmaxf(o1.y, 0.f);
      o1.z = fmaxf(o1.z, 0.f); o1.w = fmaxf(o1.w, 0.f);
    }
    *(float4*)(cp + tx * 4) = o0;
    *(float4*)(cp + 64 + tx * 4) = o1;
  }
}

// ---------------------------------------------------------------------------
// One-time W_hh transpose into coalesced-by-d layout:
//   Wt4[(k4*3 + gate)*256 + d] = float4{ W[gate*256+d][4k4 .. 4k4+3] }
// After this, in gru_rec lane d loads 16B at consecutive-d addresses:
// a wave64 load covers 1KB contiguous (was 64 separate 1KB-strided lines).
// ---------------------------------------------------------------------------
__global__ __launch_bounds__(64)
void transpose_whh(const float* __restrict__ W, float4* __restrict__ Wt)
{
  const int row = blockIdx.x;          // 0..767 = gate*256 + d
  const int k4 = threadIdx.x;          // 0..63
  const int g = row >> 8, d = row & 255;
  float4 v = *(const float4*)(W + (long)row * 256 + k4 * 4);
  Wt[((long)k4 * 3 + g) * 256 + d] = v;
}

// ---------------------------------------------------------------------------
// GRU recurrence over Tc steps. One block = 4 batch rows, 256 threads,
// 256 blocks (1/CU). Thread d owns hidden dim d for all 3 gates.
// W_hh read from the transposed layout -> fully coalesced wave loads.
// h kept in LDS (broadcast reads, conflict-free).
// ---------------------------------------------------------------------------
__global__ __launch_bounds__(256)
void gru_rec(const float* __restrict__ gi, const float4* __restrict__ Wt,
             const float* __restrict__ b_hh, float* __restrict__ h_state,
             float* __restrict__ h_out, int Tc, int store_all)
{
  __shared__ alignas(16) float hs[4][256];
  const int d = threadIdx.x;
  const int b0 = blockIdx.x * 4;
  #pragma unroll
  for (int r = 0; r < 4; ++r)
    hs[r][d] = h_state[(long)(b0 + r) * 256 + d];
  __syncthreads();

  const float bhr = b_hh[d];
  const float bhz = b_hh[256 + d];
  const float bhn = b_hh[512 + d];
  const float4* Wp = Wt + d;   // + (k4*3+gate)*256

  for (int t = 0; t < Tc; ++t) {
    float ar[4] = {0,0,0,0}, az[4] = {0,0,0,0}, an[4] = {0,0,0,0};
    #pragma unroll 4
    for (int k4 = 0; k4 < 64; ++k4) {
      float4 wr = Wp[(k4 * 3 + 0) * 256];
      float4 wz = Wp[(k4 * 3 + 1) * 256];
      float4 wn = Wp[(k4 * 3 + 2) * 256];
      #pragma unroll
      for (int r = 0; r < 4; ++r) {
        float4 hv = *(const float4*)&hs[r][k4 * 4];   // LDS broadcast
        ar[r] = fmaf(hv.x, wr.x, ar[r]); ar[r] = fmaf(hv.y, wr.y, ar[r]);
        ar[r] = fmaf(hv.z, wr.z, ar[r]); ar[r] = fmaf(hv.w, wr.w, ar[r]);
        az[r] = fmaf(hv.x, wz.x, az[r]); az[r] = fmaf(hv.y, wz.y, az[r]);
        az[r] = fmaf(hv.z, wz.z, az[r]); az[r] = fmaf(hv.w, wz.w, az[r]);
        an[r] = fmaf(hv.x, wn.x, an[r]); an[r] = fmaf(hv.y, wn.y, an[r]);
        an[r] = fmaf(hv.z, wn.z, an[r]); an[r] = fmaf(hv.w, wn.w, an[r]);
      }
    }
    float hnew[4];
    #pragma unroll
    for (int r = 0; r < 4; ++r) {
      const float* gip = gi + ((long)t * 1024 + b0 + r) * 768;
      float ir  = gip[d];
      float iz  = gip[256 + d];
      float in_ = gip[512 + d];
      float rg = 1.f / (1.f + __expf(-(ir + ar[r] + bhr)));
      float zg = 1.f / (1.f + __expf(-(iz + az[r] + bhz)));
      float ng = tanhf(in_ + rg * (an[r] + bhn));
      hnew[r] = (1.f - zg) * ng + zg * hs[r][d];
    }
    __syncthreads();   // all k-loops done reading hs before overwrite
    #pragma unroll
    for (int r = 0; r < 4; ++r) {
      hs[r][d] = hnew[r];
      if (store_all)
        h_out[((long)t * 1024 + b0 + r) * 256 + d] = hnew[r];
    }
    __syncthreads();
  }
  #pragma unroll
  for (int r = 0; r < 4; ++r)
    h_state[(long)(b0 + r) * 256 + d] = hs[r][d];
}

// ---------------------------------------------------------------------------
// Soft cluster assignment: q[b,k] ∝ 1/(1+||z_b - c_k||²)  (alpha=1), normalized.
// ---------------------------------------------------------------------------
__global__ __launch_bounds__(64)
void cluster_q(const float* __restrict__ zlat, const float* __restrict__ centers,
               float* __restrict__ q)
{
  __shared__ float red[64];
  __shared__ float qv[8];
  const int b = blockIdx.x;
  const int tid = threadIdx.x;
  const int k = tid >> 3, p = tid & 7;
  const float4* zp = (const float4*)(zlat + (long)b * 256 + p * 32);
  const float4* cp = (const float4*)(centers + (long)k * 256 + p * 32);
  float s = 0.f;
  #pragma unroll
  for (int i = 0; i < 8; ++i) {
    float4 zv = zp[i], cv = cp[i];
    float dx = zv.x - cv.x, dy = zv.y - cv.y;
    float dz = zv.z - cv.z, dw = zv.w - cv.w;
    s += dx*dx + dy*dy + dz*dz + dw*dw;
  }
  red[tid] = s;
  __syncthreads();
  if (tid < 8) {
    float d2 = 0.f;
    #pragma unroll
    for (int p2 = 0; p2 < 8; ++p2) d2 += red[tid * 8 + p2];
    qv[tid] = 1.f / (1.f + d2);
  }
  __syncthreads();
  if (tid < 8) {
    float ssum = 0.f;
    #pragma unroll
    for (int kk = 0; kk < 8; ++kk) ssum += qv[kk];
    q[(long)b * 8 + tid] = qv[tid] / ssum;
  }
}

// ---------------------------------------------------------------------------
// logits[b,k,c] = h2[b,k,:]·eW3[k,c,:] + eb3[k,c]; preds[b,c] = Σ_k q[b,k]*logits
// ---------------------------------------------------------------------------
__global__ __launch_bounds__(256)
void combine_preds(const float* __restrict__ h2, const float* __restrict__ eW3,
                   const float* __restrict__ eb3, const float* __restrict__ q,
                   float* __restrict__ out)
{
  __shared__ float p0[256], p1[256];
  __shared__ float lc[16];
  const int b = blockIdx.x;
  const int tid = threadIdx.x;
  const int k = tid >> 5, w = tid & 31;
  const float* h2p = h2 + (long)b * (8 * 256) + (long)k * 256 + w * 8;
  const float* w0  = eW3 + (long)k * 512 + w * 8;          // c=0
  const float* w1  = eW3 + (long)k * 512 + 256 + w * 8;    // c=1
  float c0 = 0.f, c1 = 0.f;
  #pragma unroll
  for (int i = 0; i < 8; ++i) {
    float hv = h2p[i];
    c0 = fmaf(hv, w0[i], c0);
    c1 = fmaf(hv, w1[i], c1);
  }
  p0[tid] = c0; p1[tid] = c1;
  __syncthreads();
  if (tid < 16) {
    int kk = tid >> 1, c = tid & 1;
    const float* pp = (c == 0) ? p0 : p1;
    float s = 0.f;
    for (int w2 = 0; w2 < 32; ++w2) s += pp[kk * 32 + w2];
    s += eb3[kk * 2 + c];
    lc[tid] = q[(long)b * 8 + kk] * s;
  }
  __syncthreads();
  if (tid < 2) {
    float s = 0.f;
    #pragma unroll
    for (int kk = 0; kk < 8; ++kk) s += lc[kk * 2 + tid];
    out[(long)b * 2 + tid] = s;
  }
}

// Zero-fill helper (avoid relying on memset semantics under graph capture)
__global__ __launch_bounds__(256)
void zero_fill(float* __restrict__ p, long n)
{
  long i = (long)blockIdx.x * 256 + threadIdx.x;
  if (i < n) p[i] = 0.f;
}

// ---------------------------------------------------------------------------
extern "C" void kernel_launch(void* const* d_in, const int* in_sizes, int n_in,
                              void* d_out, int out_size, void* d_ws, size_t ws_size,
                              hipStream_t stream)
{
  const float* x       = (const float*)d_in[0];
  const float* W_ih0   = (const float*)d_in[1];
  const float* W_hh0   = (const float*)d_in[2];
  const float* b_ih0   = (const float*)d_in[3];
  const float* b_hh0   = (const float*)d_in[4];
  const float* W_ih1   = (const float*)d_in[5];
  const float* W_hh1   = (const float*)d_in[6];
  const float* b_ih1   = (const float*)d_in[7];
  const float* b_hh1   = (const float*)d_in[8];
  const float* centers = (const float*)d_in[9];
  const float* eW1     = (const float*)d_in[10];
  const float* eb1     = (const float*)d_in[11];
  const float* eW2     = (const float*)d_in[12];
  const float* eb2     = (const float*)d_in[13];
  const float* eW3     = (const float*)d_in[14];
  const float* eb3     = (const float*)d_in[15];
  float* out = (float*)d_out;
  (void)in_sizes; (void)n_in; (void)out_size;

  // ---- workspace layout ----
  char* base = (char*)d_ws;
  size_t off = 0;
  auto alloc = [&](size_t nbytes) -> void* {
    void* p = base + off;
    off += (nbytes + 255) & ~(size_t)255;
    return p;
  };
  float* h0_state = (float*)alloc(1024ull * 256 * 4);
  float* h1_state = (float*)alloc(1024ull * 256 * 4);   // == z after layer 1
  float* qbuf     = (float*)alloc(1024ull * 8 * 4);
  float* h1buf    = (float*)alloc(1024ull * 8 * 512 * 4);
  float* h2buf    = (float*)alloc(1024ull * 8 * 256 * 4);
  float4* Wt0     = (float4*)alloc(768ull * 256 * 4);   // transposed W_hh0
  float4* Wt1     = (float4*)alloc(768ull * 256 * 4);   // transposed W_hh1
  const size_t fixed = off;

  // largest T-chunk that fits ws_size (deterministic given ws_size)
  int Tc = 1;
  const int cands[7] = {128, 64, 32, 16, 8, 4, 2};
  for (int ci = 0; ci < 7; ++ci) {
    size_t need = fixed + (size_t)cands[ci] * 1024 * (768 + 768 + 256) * 4 + 1024;
    if (need <= ws_size) { Tc = cands[ci]; break; }
  }
  float* gi0 = (float*)alloc((size_t)Tc * 1024 * 768 * 4);
  float* gi1 = (float*)alloc((size_t)Tc * 1024 * 768 * 4);
  float* h0c = (float*)alloc((size_t)Tc * 1024 * 256 * 4);

  // ---- zero recurrent states; transpose W_hh (once per call) ----
  {
    long n = 2L * 1024 * 256;   // h0_state + h1_state are contiguous
    zero_fill<<<dim3((unsigned)((n + 255) / 256)), 256, 0, stream>>>(h0_state, n);
    transpose_whh<<<768, 64, 0, stream>>>(W_hh0, Wt0);
    transpose_whh<<<768, 64, 0, stream>>>(W_hh1, Wt1);
  }

  // ---- 2-layer GRU, chunked over time ----
  for (int t0 = 0; t0 < 128; t0 += Tc) {
    // gi0[tl,b,:] = x[b, t0+tl, :] @ W_ih0^T + b_ih0
    gemm_f32<0><<<dim3(6, Tc * 8, 1), 256, 0, stream>>>(
        x + (long)t0 * 128, W_ih0, b_ih0, gi0, 128,
        /*a_sT*/ 128, /*a_sB*/ 128L * 128, /*a_sZ*/ 0,
        /*w_sZ*/ 0, /*b_sZ*/ 0, /*c_row*/ 768, /*c_sZ*/ 0);
    gru_rec<<<256, 256, 0, stream>>>(gi0, Wt0, b_hh0, h0_state, h0c, Tc, 1);

    // gi1[tl,b,:] = h0c[tl,b,:] @ W_ih1^T + b_ih1
    gemm_f32<0><<<dim3(6, Tc * 8, 1), 256, 0, stream>>>(
        h0c, W_ih1, b_ih1, gi1, 256,
        /*a_sT*/ 1024L * 256, /*a_sB*/ 256, /*a_sZ*/ 0,
        /*w_sZ*/ 0, /*b_sZ*/ 0, /*c_row*/ 768, /*c_sZ*/ 0);
    gru_rec<<<256, 256, 0, stream>>>(gi1, Wt1, b_hh1, h1_state, nullptr, Tc, 0);
  }

  // ---- soft cluster assignment ----
  cluster_q<<<1024, 64, 0, stream>>>(h1_state, centers, qbuf);

  // ---- experts: h1 = relu(z @ eW1[k]^T + eb1[k]) ----
  gemm_f32<1><<<dim3(4, 8, 8), 256, 0, stream>>>(
      h1_state, eW1, eb1, h1buf, 256,
      /*a_sT*/ 0, /*a_sB*/ 256, /*a_sZ*/ 0,
      /*w_sZ*/ 512L * 256, /*b_sZ*/ 512, /*c_row*/ 8L * 512, /*c_sZ*/ 512);
  // h2 = relu(h1 @ eW2[k]^T + eb2[k])
  gemm_f32<1><<<dim3(2, 8, 8), 256, 0, stream>>>(
      h1buf, eW2, eb2, h2buf, 512,
      /*a_sT*/ 0, /*a_sB*/ 8L * 512, /*a_sZ*/ 512,
      /*w_sZ*/ 256L * 512, /*b_sZ*/ 256, /*c_row*/ 8L * 256, /*c_sZ*/ 256);

  // ---- logits + q-weighted combine ----
  combine_preds<<<1024, 256, 0, stream>>>(h2buf, eW3, eb3, qbuf, out);
}

// Round 4
// 3497.924 us; speedup vs baseline: 3.5806x; 1.2818x over previous
//
#include <hip/hip_runtime.h>
#include <math.h>

// Problem dims (fixed by reference)
//  B=1024, T=128, I=128, H=256, 3H=768, K=8, E1=512, E2=256, C=2

// ---------------------------------------------------------------------------
// fp32 GEMM, 128x128 tile, 256 threads, 8x8 per-thread microtile.
// ---------------------------------------------------------------------------
template<int ACT>
__global__ __launch_bounds__(256)
void gemm_f32(const float* __restrict__ A, const float* __restrict__ W,
              const float* __restrict__ bias, float* __restrict__ C,
              int K,
              long a_sT, long a_sB, long a_sZ,
              long w_sZ, long b_sZ, long c_row, long c_sZ)
{
  __shared__ alignas(16) float As[16][132];
  __shared__ alignas(16) float Ws[16][132];
  const int z = blockIdx.z;
  const float* Az = A + (long)z * a_sZ;
  const float* Wz = W + (long)z * w_sZ;
  const float* bz = bias + (long)z * b_sZ;
  const int m0 = blockIdx.y * 128;
  const int n0 = blockIdx.x * 128;
  const int tid = threadIdx.x;
  const int tx = tid & 15, ty = tid >> 4;

  const int row0 = tid >> 2, kq0 = tid & 3;
  const int row1 = (tid + 256) >> 2, kq1 = kq0;

  float acc[8][8];
  #pragma unroll
  for (int i = 0; i < 8; ++i)
    #pragma unroll
    for (int j = 0; j < 8; ++j) acc[i][j] = 0.f;

  const int ma0 = m0 + row0, ma1 = m0 + row1;
  const float* apr0 = Az + (long)(ma0 >> 10) * a_sT + (long)(ma0 & 1023) * a_sB + kq0 * 4;
  const float* apr1 = Az + (long)(ma1 >> 10) * a_sT + (long)(ma1 & 1023) * a_sB + kq1 * 4;
  const float* wpr0 = Wz + (long)(n0 + row0) * K + kq0 * 4;
  const float* wpr1 = Wz + (long)(n0 + row1) * K + kq1 * 4;

  float4 pa0 = *(const float4*)(apr0);
  float4 pa1 = *(const float4*)(apr1);
  float4 pw0 = *(const float4*)(wpr0);
  float4 pw1 = *(const float4*)(wpr1);

  for (int k0 = 0; k0 < K; k0 += 16) {
    As[kq0*4+0][row0] = pa0.x; As[kq0*4+1][row0] = pa0.y;
    As[kq0*4+2][row0] = pa0.z; As[kq0*4+3][row0] = pa0.w;
    As[kq1*4+0][row1] = pa1.x; As[kq1*4+1][row1] = pa1.y;
    As[kq1*4+2][row1] = pa1.z; As[kq1*4+3][row1] = pa1.w;
    Ws[kq0*4+0][row0] = pw0.x; Ws[kq0*4+1][row0] = pw0.y;
    Ws[kq0*4+2][row0] = pw0.z; Ws[kq0*4+3][row0] = pw0.w;
    Ws[kq1*4+0][row1] = pw1.x; Ws[kq1*4+1][row1] = pw1.y;
    Ws[kq1*4+2][row1] = pw1.z; Ws[kq1*4+3][row1] = pw1.w;
    __syncthreads();

    if (k0 + 16 < K) {
      pa0 = *(const float4*)(apr0 + k0 + 16);
      pa1 = *(const float4*)(apr1 + k0 + 16);
      pw0 = *(const float4*)(wpr0 + k0 + 16);
      pw1 = *(const float4*)(wpr1 + k0 + 16);
    }

    #pragma unroll
    for (int kk = 0; kk < 16; ++kk) {
      float4 a0 = *(const float4*)&As[kk][ty * 8];
      float4 a1 = *(const float4*)&As[kk][ty * 8 + 4];
      float4 b0 = *(const float4*)&Ws[kk][tx * 4];
      float4 b1 = *(const float4*)&Ws[kk][64 + tx * 4];
      float a[8] = {a0.x,a0.y,a0.z,a0.w,a1.x,a1.y,a1.z,a1.w};
      float b[8] = {b0.x,b0.y,b0.z,b0.w,b1.x,b1.y,b1.z,b1.w};
      #pragma unroll
      for (int i = 0; i < 8; ++i)
        #pragma unroll
        for (int j = 0; j < 8; ++j)
          acc[i][j] = fmaf(a[i], b[j], acc[i][j]);
    }
    __syncthreads();
  }

  float4 bv0 = *(const float4*)&bz[n0 + tx * 4];
  float4 bv1 = *(const float4*)&bz[n0 + 64 + tx * 4];
  #pragma unroll
  for (int i = 0; i < 8; ++i) {
    int m = m0 + ty * 8 + i;
    float* cp = C + (long)m * c_row + (long)z * c_sZ + n0;
    float4 o0, o1;
    o0.x = acc[i][0] + bv0.x; o0.y = acc[i][1] + bv0.y;
    o0.z = acc[i][2] + bv0.z; o0.w = acc[i][3] + bv0.w;
    o1.x = acc[i][4] + bv1.x; o1.y = acc[i][5] + bv1.y;
    o1.z = acc[i][6] + bv1.z; o1.w = acc[i][7] + bv1.w;
    if (ACT == 1) {
      o0.x = fmaxf(o0.x, 0.f); o0.y = fmaxf(o0.y, 0.f);
      o0.z = fmaxf(o0.z, 0.f); o0.w = fmaxf(o0.w, 0.f);
      o1.x = fmaxf(o1.x, 0.f); o1.y = fmaxf(o1.y, 0.f);
      o1.z = fmaxf(o1.z, 0.f); o1.w = fmaxf(o1.w, 0.f);
    }
    *(float4*)(cp + tx * 4) = o0;
    *(float4*)(cp + 64 + tx * 4) = o1;
  }
}

// ---------------------------------------------------------------------------
// One-time W_hh transpose into coalesced-by-d layout:
//   Wt4[(k4*3 + gate)*256 + d] = float4{ W[gate*256+d][4k4 .. 4k4+3] }
// ---------------------------------------------------------------------------
__global__ __launch_bounds__(64)
void transpose_whh(const float* __restrict__ W, float4* __restrict__ Wt)
{
  const int row = blockIdx.x;          // 0..767 = gate*256 + d
  const int k4 = threadIdx.x;          // 0..63
  const int g = row >> 8, d = row & 255;
  float4 v = *(const float4*)(W + (long)row * 256 + k4 * 4);
  Wt[((long)k4 * 3 + g) * 256 + d] = v;
}

// ---------------------------------------------------------------------------
// GRU recurrence, split-K: 256 blocks x 512 threads; block = 4 batch rows.
// Thread (d = tid&255, half = tid>>8) computes the k in [128*half, 128*half+128)
// partial of all 3 gate dots for 4 rows. Half-1 writes partials to LDS; half-0
// reduces, applies activations, updates h. 8 waves/CU (2/SIMD) hides the
// W L2-stream + LDS-broadcast latency that pinned round-3 at 36% VALUBusy.
// W traffic per block unchanged (each half reads its k-half of Wt).
// ---------------------------------------------------------------------------
__global__ __launch_bounds__(512)
void gru_rec(const float* __restrict__ gi, const float4* __restrict__ Wt,
             const float* __restrict__ b_hh, float* __restrict__ h_state,
             float* __restrict__ h_out, int Tc, int store_all)
{
  __shared__ alignas(16) float hs[4][256];
  __shared__ alignas(16) float part[12][256];   // [gate*4 + r][d], from half 1
  const int tid = threadIdx.x;
  const int d = tid & 255;
  const int half = tid >> 8;            // 0 or 1
  const int b0 = blockIdx.x * 4;
  if (half == 0) {
    #pragma unroll
    for (int r = 0; r < 4; ++r)
      hs[r][d] = h_state[(long)(b0 + r) * 256 + d];
  }
  __syncthreads();

  const float bhr = b_hh[d];
  const float bhz = b_hh[256 + d];
  const float bhn = b_hh[512 + d];
  const int k4lo = half * 32;           // this half's k4 range: 32 iters
  const float4* Wp = Wt + d;            // + (k4*3+gate)*256

  for (int t = 0; t < Tc; ++t) {
    float ar[4] = {0,0,0,0}, az[4] = {0,0,0,0}, an[4] = {0,0,0,0};
    #pragma unroll 4
    for (int k4i = 0; k4i < 32; ++k4i) {
      const int k4 = k4lo + k4i;
      float4 wr = Wp[(k4 * 3 + 0) * 256];
      float4 wz = Wp[(k4 * 3 + 1) * 256];
      float4 wn = Wp[(k4 * 3 + 2) * 256];
      #pragma unroll
      for (int r = 0; r < 4; ++r) {
        float4 hv = *(const float4*)&hs[r][k4 * 4];   // LDS broadcast
        ar[r] = fmaf(hv.x, wr.x, ar[r]); ar[r] = fmaf(hv.y, wr.y, ar[r]);
        ar[r] = fmaf(hv.z, wr.z, ar[r]); ar[r] = fmaf(hv.w, wr.w, ar[r]);
        az[r] = fmaf(hv.x, wz.x, az[r]); az[r] = fmaf(hv.y, wz.y, az[r]);
        az[r] = fmaf(hv.z, wz.z, az[r]); az[r] = fmaf(hv.w, wz.w, az[r]);
        an[r] = fmaf(hv.x, wn.x, an[r]); an[r] = fmaf(hv.y, wn.y, an[r]);
        an[r] = fmaf(hv.z, wn.z, an[r]); an[r] = fmaf(hv.w, wn.w, an[r]);
      }
    }
    if (half == 1) {
      #pragma unroll
      for (int r = 0; r < 4; ++r) {
        part[0 * 4 + r][d] = ar[r];
        part[1 * 4 + r][d] = az[r];
        part[2 * 4 + r][d] = an[r];
      }
    }
    __syncthreads();   // partials visible; everyone done reading hs for step t
    if (half == 0) {
      #pragma unroll
      for (int r = 0; r < 4; ++r) {
        const float* gip = gi + ((long)t * 1024 + b0 + r) * 768;
        float ir  = gip[d];
        float iz  = gip[256 + d];
        float in_ = gip[512 + d];
        float sr = ar[r] + part[0 * 4 + r][d];
        float sz = az[r] + part[1 * 4 + r][d];
        float sn = an[r] + part[2 * 4 + r][d];
        float rg = 1.f / (1.f + __expf(-(ir + sr + bhr)));
        float zg = 1.f / (1.f + __expf(-(iz + sz + bhz)));
        float ng = tanhf(in_ + rg * (sn + bhn));
        float hn = (1.f - zg) * ng + zg * hs[r][d];
        hs[r][d] = hn;   // safe: only thread (d, half=0) touches hs[r][d] now
        if (store_all)
          h_out[((long)t * 1024 + b0 + r) * 256 + d] = hn;
      }
    }
    __syncthreads();   // new h visible to both halves for step t+1
  }
  if (half == 0) {
    #pragma unroll
    for (int r = 0; r < 4; ++r)
      h_state[(long)(b0 + r) * 256 + d] = hs[r][d];
  }
}

// ---------------------------------------------------------------------------
// Soft cluster assignment: q[b,k] ∝ 1/(1+||z_b - c_k||²)  (alpha=1), normalized.
// ---------------------------------------------------------------------------
__global__ __launch_bounds__(64)
void cluster_q(const float* __restrict__ zlat, const float* __restrict__ centers,
               float* __restrict__ q)
{
  __shared__ float red[64];
  __shared__ float qv[8];
  const int b = blockIdx.x;
  const int tid = threadIdx.x;
  const int k = tid >> 3, p = tid & 7;
  const float4* zp = (const float4*)(zlat + (long)b * 256 + p * 32);
  const float4* cp = (const float4*)(centers + (long)k * 256 + p * 32);
  float s = 0.f;
  #pragma unroll
  for (int i = 0; i < 8; ++i) {
    float4 zv = zp[i], cv = cp[i];
    float dx = zv.x - cv.x, dy = zv.y - cv.y;
    float dz = zv.z - cv.z, dw = zv.w - cv.w;
    s += dx*dx + dy*dy + dz*dz + dw*dw;
  }
  red[tid] = s;
  __syncthreads();
  if (tid < 8) {
    float d2 = 0.f;
    #pragma unroll
    for (int p2 = 0; p2 < 8; ++p2) d2 += red[tid * 8 + p2];
    qv[tid] = 1.f / (1.f + d2);
  }
  __syncthreads();
  if (tid < 8) {
    float ssum = 0.f;
    #pragma unroll
    for (int kk = 0; kk < 8; ++kk) ssum += qv[kk];
    q[(long)b * 8 + tid] = qv[tid] / ssum;
  }
}

// ---------------------------------------------------------------------------
// logits[b,k,c] = h2[b,k,:]·eW3[k,c,:] + eb3[k,c]; preds[b,c] = Σ_k q[b,k]*logits
// ---------------------------------------------------------------------------
__global__ __launch_bounds__(256)
void combine_preds(const float* __restrict__ h2, const float* __restrict__ eW3,
                   const float* __restrict__ eb3, const float* __restrict__ q,
                   float* __restrict__ out)
{
  __shared__ float p0[256], p1[256];
  __shared__ float lc[16];
  const int b = blockIdx.x;
  const int tid = threadIdx.x;
  const int k = tid >> 5, w = tid & 31;
  const float* h2p = h2 + (long)b * (8 * 256) + (long)k * 256 + w * 8;
  const float* w0  = eW3 + (long)k * 512 + w * 8;          // c=0
  const float* w1  = eW3 + (long)k * 512 + 256 + w * 8;    // c=1
  float c0 = 0.f, c1 = 0.f;
  #pragma unroll
  for (int i = 0; i < 8; ++i) {
    float hv = h2p[i];
    c0 = fmaf(hv, w0[i], c0);
    c1 = fmaf(hv, w1[i], c1);
  }
  p0[tid] = c0; p1[tid] = c1;
  __syncthreads();
  if (tid < 16) {
    int kk = tid >> 1, c = tid & 1;
    const float* pp = (c == 0) ? p0 : p1;
    float s = 0.f;
    for (int w2 = 0; w2 < 32; ++w2) s += pp[kk * 32 + w2];
    s += eb3[kk * 2 + c];
    lc[tid] = q[(long)b * 8 + kk] * s;
  }
  __syncthreads();
  if (tid < 2) {
    float s = 0.f;
    #pragma unroll
    for (int kk = 0; kk < 8; ++kk) s += lc[kk * 2 + tid];
    out[(long)b * 2 + tid] = s;
  }
}

// Zero-fill helper (avoid relying on memset semantics under graph capture)
__global__ __launch_bounds__(256)
void zero_fill(float* __restrict__ p, long n)
{
  long i = (long)blockIdx.x * 256 + threadIdx.x;
  if (i < n) p[i] = 0.f;
}

// ---------------------------------------------------------------------------
extern "C" void kernel_launch(void* const* d_in, const int* in_sizes, int n_in,
                              void* d_out, int out_size, void* d_ws, size_t ws_size,
                              hipStream_t stream)
{
  const float* x       = (const float*)d_in[0];
  const float* W_ih0   = (const float*)d_in[1];
  const float* W_hh0   = (const float*)d_in[2];
  const float* b_ih0   = (const float*)d_in[3];
  const float* b_hh0   = (const float*)d_in[4];
  const float* W_ih1   = (const float*)d_in[5];
  const float* W_hh1   = (const float*)d_in[6];
  const float* b_ih1   = (const float*)d_in[7];
  const float* b_hh1   = (const float*)d_in[8];
  const float* centers = (const float*)d_in[9];
  const float* eW1     = (const float*)d_in[10];
  const float* eb1     = (const float*)d_in[11];
  const float* eW2     = (const float*)d_in[12];
  const float* eb2     = (const float*)d_in[13];
  const float* eW3     = (const float*)d_in[14];
  const float* eb3     = (const float*)d_in[15];
  float* out = (float*)d_out;
  (void)in_sizes; (void)n_in; (void)out_size;

  // ---- workspace layout ----
  char* base = (char*)d_ws;
  size_t off = 0;
  auto alloc = [&](size_t nbytes) -> void* {
    void* p = base + off;
    off += (nbytes + 255) & ~(size_t)255;
    return p;
  };
  float* h0_state = (float*)alloc(1024ull * 256 * 4);
  float* h1_state = (float*)alloc(1024ull * 256 * 4);   // == z after layer 1
  float* qbuf     = (float*)alloc(1024ull * 8 * 4);
  float* h1buf    = (float*)alloc(1024ull * 8 * 512 * 4);
  float* h2buf    = (float*)alloc(1024ull * 8 * 256 * 4);
  float4* Wt0     = (float4*)alloc(768ull * 256 * 4);   // transposed W_hh0
  float4* Wt1     = (float4*)alloc(768ull * 256 * 4);   // transposed W_hh1
  const size_t fixed = off;

  // largest T-chunk that fits ws_size (deterministic given ws_size)
  int Tc = 1;
  const int cands[7] = {128, 64, 32, 16, 8, 4, 2};
  for (int ci = 0; ci < 7; ++ci) {
    size_t need = fixed + (size_t)cands[ci] * 1024 * (768 + 768 + 256) * 4 + 1024;
    if (need <= ws_size) { Tc = cands[ci]; break; }
  }
  float* gi0 = (float*)alloc((size_t)Tc * 1024 * 768 * 4);
  float* gi1 = (float*)alloc((size_t)Tc * 1024 * 768 * 4);
  float* h0c = (float*)alloc((size_t)Tc * 1024 * 256 * 4);

  // ---- zero recurrent states; transpose W_hh (once per call) ----
  {
    long n = 2L * 1024 * 256;   // h0_state + h1_state are contiguous
    zero_fill<<<dim3((unsigned)((n + 255) / 256)), 256, 0, stream>>>(h0_state, n);
    transpose_whh<<<768, 64, 0, stream>>>(W_hh0, Wt0);
    transpose_whh<<<768, 64, 0, stream>>>(W_hh1, Wt1);
  }

  // ---- 2-layer GRU, chunked over time ----
  for (int t0 = 0; t0 < 128; t0 += Tc) {
    // gi0[tl,b,:] = x[b, t0+tl, :] @ W_ih0^T + b_ih0
    gemm_f32<0><<<dim3(6, Tc * 8, 1), 256, 0, stream>>>(
        x + (long)t0 * 128, W_ih0, b_ih0, gi0, 128,
        /*a_sT*/ 128, /*a_sB*/ 128L * 128, /*a_sZ*/ 0,
        /*w_sZ*/ 0, /*b_sZ*/ 0, /*c_row*/ 768, /*c_sZ*/ 0);
    gru_rec<<<256, 512, 0, stream>>>(gi0, Wt0, b_hh0, h0_state, h0c, Tc, 1);

    // gi1[tl,b,:] = h0c[tl,b,:] @ W_ih1^T + b_ih1
    gemm_f32<0><<<dim3(6, Tc * 8, 1), 256, 0, stream>>>(
        h0c, W_ih1, b_ih1, gi1, 256,
        /*a_sT*/ 1024L * 256, /*a_sB*/ 256, /*a_sZ*/ 0,
        /*w_sZ*/ 0, /*b_sZ*/ 0, /*c_row*/ 768, /*c_sZ*/ 0);
    gru_rec<<<256, 512, 0, stream>>>(gi1, Wt1, b_hh1, h1_state, nullptr, Tc, 0);
  }

  // ---- soft cluster assignment ----
  cluster_q<<<1024, 64, 0, stream>>>(h1_state, centers, qbuf);

  // ---- experts: h1 = relu(z @ eW1[k]^T + eb1[k]) ----
  gemm_f32<1><<<dim3(4, 8, 8), 256, 0, stream>>>(
      h1_state, eW1, eb1, h1buf, 256,
      /*a_sT*/ 0, /*a_sB*/ 256, /*a_sZ*/ 0,
      /*w_sZ*/ 512L * 256, /*b_sZ*/ 512, /*c_row*/ 8L * 512, /*c_sZ*/ 512);
  // h2 = relu(h1 @ eW2[k]^T + eb2[k])
  gemm_f32<1><<<dim3(2, 8, 8), 256, 0, stream>>>(
      h1buf, eW2, eb2, h2buf, 512,
      /*a_sT*/ 0, /*a_sB*/ 8L * 512, /*a_sZ*/ 512,
      /*w_sZ*/ 256L * 512, /*b_sZ*/ 256, /*c_row*/ 8L * 256, /*c_sZ*/ 256);

  // ---- logits + q-weighted combine ----
  combine_preds<<<1024, 256, 0, stream>>>(h2buf, eW3, eb3, qbuf, out);
}

// Round 5
// 3322.511 us; speedup vs baseline: 3.7697x; 1.0528x over previous
//
#include <hip/hip_runtime.h>
#include <math.h>

// Problem dims (fixed by reference)
//  B=1024, T=128, I=128, H=256, 3H=768, K=8, E1=512, E2=256, C=2

// ---------------------------------------------------------------------------
// fp32 GEMM, 128x128 tile, 256 threads, 8x8 per-thread microtile.
// ---------------------------------------------------------------------------
template<int ACT>
__global__ __launch_bounds__(256)
void gemm_f32(const float* __restrict__ A, const float* __restrict__ W,
              const float* __restrict__ bias, float* __restrict__ C,
              int K,
              long a_sT, long a_sB, long a_sZ,
              long w_sZ, long b_sZ, long c_row, long c_sZ)
{
  __shared__ alignas(16) float As[16][132];
  __shared__ alignas(16) float Ws[16][132];
  const int z = blockIdx.z;
  const float* Az = A + (long)z * a_sZ;
  const float* Wz = W + (long)z * w_sZ;
  const float* bz = bias + (long)z * b_sZ;
  const int m0 = blockIdx.y * 128;
  const int n0 = blockIdx.x * 128;
  const int tid = threadIdx.x;
  const int tx = tid & 15, ty = tid >> 4;

  const int row0 = tid >> 2, kq0 = tid & 3;
  const int row1 = (tid + 256) >> 2, kq1 = kq0;

  float acc[8][8];
  #pragma unroll
  for (int i = 0; i < 8; ++i)
    #pragma unroll
    for (int j = 0; j < 8; ++j) acc[i][j] = 0.f;

  const int ma0 = m0 + row0, ma1 = m0 + row1;
  const float* apr0 = Az + (long)(ma0 >> 10) * a_sT + (long)(ma0 & 1023) * a_sB + kq0 * 4;
  const float* apr1 = Az + (long)(ma1 >> 10) * a_sT + (long)(ma1 & 1023) * a_sB + kq1 * 4;
  const float* wpr0 = Wz + (long)(n0 + row0) * K + kq0 * 4;
  const float* wpr1 = Wz + (long)(n0 + row1) * K + kq1 * 4;

  float4 pa0 = *(const float4*)(apr0);
  float4 pa1 = *(const float4*)(apr1);
  float4 pw0 = *(const float4*)(wpr0);
  float4 pw1 = *(const float4*)(wpr1);

  for (int k0 = 0; k0 < K; k0 += 16) {
    As[kq0*4+0][row0] = pa0.x; As[kq0*4+1][row0] = pa0.y;
    As[kq0*4+2][row0] = pa0.z; As[kq0*4+3][row0] = pa0.w;
    As[kq1*4+0][row1] = pa1.x; As[kq1*4+1][row1] = pa1.y;
    As[kq1*4+2][row1] = pa1.z; As[kq1*4+3][row1] = pa1.w;
    Ws[kq0*4+0][row0] = pw0.x; Ws[kq0*4+1][row0] = pw0.y;
    Ws[kq0*4+2][row0] = pw0.z; Ws[kq0*4+3][row0] = pw0.w;
    Ws[kq1*4+0][row1] = pw1.x; Ws[kq1*4+1][row1] = pw1.y;
    Ws[kq1*4+2][row1] = pw1.z; Ws[kq1*4+3][row1] = pw1.w;
    __syncthreads();

    if (k0 + 16 < K) {
      pa0 = *(const float4*)(apr0 + k0 + 16);
      pa1 = *(const float4*)(apr1 + k0 + 16);
      pw0 = *(const float4*)(wpr0 + k0 + 16);
      pw1 = *(const float4*)(wpr1 + k0 + 16);
    }

    #pragma unroll
    for (int kk = 0; kk < 16; ++kk) {
      float4 a0 = *(const float4*)&As[kk][ty * 8];
      float4 a1 = *(const float4*)&As[kk][ty * 8 + 4];
      float4 b0 = *(const float4*)&Ws[kk][tx * 4];
      float4 b1 = *(const float4*)&Ws[kk][64 + tx * 4];
      float a[8] = {a0.x,a0.y,a0.z,a0.w,a1.x,a1.y,a1.z,a1.w};
      float b[8] = {b0.x,b0.y,b0.z,b0.w,b1.x,b1.y,b1.z,b1.w};
      #pragma unroll
      for (int i = 0; i < 8; ++i)
        #pragma unroll
        for (int j = 0; j < 8; ++j)
          acc[i][j] = fmaf(a[i], b[j], acc[i][j]);
    }
    __syncthreads();
  }

  float4 bv0 = *(const float4*)&bz[n0 + tx * 4];
  float4 bv1 = *(const float4*)&bz[n0 + 64 + tx * 4];
  #pragma unroll
  for (int i = 0; i < 8; ++i) {
    int m = m0 + ty * 8 + i;
    float* cp = C + (long)m * c_row + (long)z * c_sZ + n0;
    float4 o0, o1;
    o0.x = acc[i][0] + bv0.x; o0.y = acc[i][1] + bv0.y;
    o0.z = acc[i][2] + bv0.z; o0.w = acc[i][3] + bv0.w;
    o1.x = acc[i][4] + bv1.x; o1.y = acc[i][5] + bv1.y;
    o1.z = acc[i][6] + bv1.z; o1.w = acc[i][7] + bv1.w;
    if (ACT == 1) {
      o0.x = fmaxf(o0.x, 0.f); o0.y = fmaxf(o0.y, 0.f);
      o0.z = fmaxf(o0.z, 0.f); o0.w = fmaxf(o0.w, 0.f);
      o1.x = fmaxf(o1.x, 0.f); o1.y = fmaxf(o1.y, 0.f);
      o1.z = fmaxf(o1.z, 0.f); o1.w = fmaxf(o1.w, 0.f);
    }
    *(float4*)(cp + tx * 4) = o0;
    *(float4*)(cp + 64 + tx * 4) = o1;
  }
}

// ---------------------------------------------------------------------------
// One-time W_hh transpose into coalesced-by-d layout:
//   Wt4[(k4*3 + gate)*256 + d] = float4{ W[gate*256+d][4k4 .. 4k4+3] }
// ---------------------------------------------------------------------------
__global__ __launch_bounds__(64)
void transpose_whh(const float* __restrict__ W, float4* __restrict__ Wt)
{
  const int row = blockIdx.x;          // 0..767 = gate*256 + d
  const int k4 = threadIdx.x;          // 0..63
  const int g = row >> 8, d = row & 255;
  float4 v = *(const float4*)(W + (long)row * 256 + k4 * 4);
  Wt[((long)k4 * 3 + g) * 256 + d] = v;
}

// ---------------------------------------------------------------------------
// GRU recurrence, 4-way split-K: 256 blocks x 1024 threads; block = 4 batch
// rows. Thread (d = tid&255, q = tid>>8) computes the k in [64q, 64q+64)
// partial of all 3 gate dots for 4 rows. All quarters write partials to LDS;
// quarter q then owns batch row q's reduction + activation + h update
// (balanced epilogue). 16 waves/CU (4/SIMD) for latency hiding; W traffic
// per block unchanged (each quarter reads its k-quarter of Wt).
// Per-row gi loads hoisted before the k-loop to overlap their latency.
// ---------------------------------------------------------------------------
__global__ __launch_bounds__(1024)
void gru_rec(const float* __restrict__ gi, const float4* __restrict__ Wt,
             const float* __restrict__ b_hh, float* __restrict__ h_state,
             float* __restrict__ h_out, int Tc, int store_all)
{
  __shared__ alignas(16) float hs[4][256];
  __shared__ float part[4][12][256];   // [quarter][gate*4 + row][d]
  const int tid = threadIdx.x;
  const int d = tid & 255;
  const int q = tid >> 8;               // 0..3: k-quarter AND owned batch row
  const int b0 = blockIdx.x * 4;
  hs[q][d] = h_state[(long)(b0 + q) * 256 + d];   // quarter q loads row q
  __syncthreads();

  const float bhr = b_hh[d];
  const float bhz = b_hh[256 + d];
  const float bhn = b_hh[512 + d];
  const int k4lo = q * 16;              // this quarter's 16 k4 iters
  const float4* Wp = Wt + d;            // + (k4*3+gate)*256

  for (int t = 0; t < Tc; ++t) {
    // own-row gi loads issued up front; latency overlaps the k-loop
    const float* gip = gi + ((long)t * 1024 + b0 + q) * 768;
    const float gir = gip[d];
    const float giz = gip[256 + d];
    const float gin = gip[512 + d];

    float ar[4] = {0,0,0,0}, az[4] = {0,0,0,0}, an[4] = {0,0,0,0};
    #pragma unroll 8
    for (int k4i = 0; k4i < 16; ++k4i) {
      const int k4 = k4lo + k4i;
      float4 wr = Wp[(k4 * 3 + 0) * 256];
      float4 wz = Wp[(k4 * 3 + 1) * 256];
      float4 wn = Wp[(k4 * 3 + 2) * 256];
      #pragma unroll
      for (int r = 0; r < 4; ++r) {
        float4 hv = *(const float4*)&hs[r][k4 * 4];   // LDS broadcast
        ar[r] = fmaf(hv.x, wr.x, ar[r]); ar[r] = fmaf(hv.y, wr.y, ar[r]);
        ar[r] = fmaf(hv.z, wr.z, ar[r]); ar[r] = fmaf(hv.w, wr.w, ar[r]);
        az[r] = fmaf(hv.x, wz.x, az[r]); az[r] = fmaf(hv.y, wz.y, az[r]);
        az[r] = fmaf(hv.z, wz.z, az[r]); az[r] = fmaf(hv.w, wz.w, az[r]);
        an[r] = fmaf(hv.x, wn.x, an[r]); an[r] = fmaf(hv.y, wn.y, an[r]);
        an[r] = fmaf(hv.z, wn.z, an[r]); an[r] = fmaf(hv.w, wn.w, an[r]);
      }
    }
    #pragma unroll
    for (int r = 0; r < 4; ++r) {
      part[q][0 * 4 + r][d] = ar[r];
      part[q][1 * 4 + r][d] = az[r];
      part[q][2 * 4 + r][d] = an[r];
    }
    __syncthreads();   // partials visible; all quarters done reading hs

    // quarter q reduces + activates its own row q
    {
      float sr = ar[q], sz = az[q], sn = an[q];
      #pragma unroll
      for (int qq = 0; qq < 4; ++qq) {
        if (qq == q) continue;
        sr += part[qq][0 * 4 + q][d];
        sz += part[qq][1 * 4 + q][d];
        sn += part[qq][2 * 4 + q][d];
      }
      float rg = 1.f / (1.f + __expf(-(gir + sr + bhr)));
      float zg = 1.f / (1.f + __expf(-(giz + sz + bhz)));
      float ng = tanhf(gin + rg * (sn + bhn));
      float hn = (1.f - zg) * ng + zg * hs[q][d];
      hs[q][d] = hn;   // only thread (q,d) touches hs[q][d] in this region
      if (store_all)
        h_out[((long)t * 1024 + b0 + q) * 256 + d] = hn;
    }
    __syncthreads();   // new h visible to all quarters for step t+1
  }
  h_state[(long)(b0 + q) * 256 + d] = hs[q][d];
}

// ---------------------------------------------------------------------------
// Soft cluster assignment: q[b,k] ∝ 1/(1+||z_b - c_k||²)  (alpha=1), normalized.
// ---------------------------------------------------------------------------
__global__ __launch_bounds__(64)
void cluster_q(const float* __restrict__ zlat, const float* __restrict__ centers,
               float* __restrict__ q)
{
  __shared__ float red[64];
  __shared__ float qv[8];
  const int b = blockIdx.x;
  const int tid = threadIdx.x;
  const int k = tid >> 3, p = tid & 7;
  const float4* zp = (const float4*)(zlat + (long)b * 256 + p * 32);
  const float4* cp = (const float4*)(centers + (long)k * 256 + p * 32);
  float s = 0.f;
  #pragma unroll
  for (int i = 0; i < 8; ++i) {
    float4 zv = zp[i], cv = cp[i];
    float dx = zv.x - cv.x, dy = zv.y - cv.y;
    float dz = zv.z - cv.z, dw = zv.w - cv.w;
    s += dx*dx + dy*dy + dz*dz + dw*dw;
  }
  red[tid] = s;
  __syncthreads();
  if (tid < 8) {
    float d2 = 0.f;
    #pragma unroll
    for (int p2 = 0; p2 < 8; ++p2) d2 += red[tid * 8 + p2];
    qv[tid] = 1.f / (1.f + d2);
  }
  __syncthreads();
  if (tid < 8) {
    float ssum = 0.f;
    #pragma unroll
    for (int kk = 0; kk < 8; ++kk) ssum += qv[kk];
    q[(long)b * 8 + tid] = qv[tid] / ssum;
  }
}

// ---------------------------------------------------------------------------
// logits[b,k,c] = h2[b,k,:]·eW3[k,c,:] + eb3[k,c]; preds[b,c] = Σ_k q[b,k]*logits
// ---------------------------------------------------------------------------
__global__ __launch_bounds__(256)
void combine_preds(const float* __restrict__ h2, const float* __restrict__ eW3,
                   const float* __restrict__ eb3, const float* __restrict__ q,
                   float* __restrict__ out)
{
  __shared__ float p0[256], p1[256];
  __shared__ float lc[16];
  const int b = blockIdx.x;
  const int tid = threadIdx.x;
  const int k = tid >> 5, w = tid & 31;
  const float* h2p = h2 + (long)b * (8 * 256) + (long)k * 256 + w * 8;
  const float* w0  = eW3 + (long)k * 512 + w * 8;          // c=0
  const float* w1  = eW3 + (long)k * 512 + 256 + w * 8;    // c=1
  float c0 = 0.f, c1 = 0.f;
  #pragma unroll
  for (int i = 0; i < 8; ++i) {
    float hv = h2p[i];
    c0 = fmaf(hv, w0[i], c0);
    c1 = fmaf(hv, w1[i], c1);
  }
  p0[tid] = c0; p1[tid] = c1;
  __syncthreads();
  if (tid < 16) {
    int kk = tid >> 1, c = tid & 1;
    const float* pp = (c == 0) ? p0 : p1;
    float s = 0.f;
    for (int w2 = 0; w2 < 32; ++w2) s += pp[kk * 32 + w2];
    s += eb3[kk * 2 + c];
    lc[tid] = q[(long)b * 8 + kk] * s;
  }
  __syncthreads();
  if (tid < 2) {
    float s = 0.f;
    #pragma unroll
    for (int kk = 0; kk < 8; ++kk) s += lc[kk * 2 + tid];
    out[(long)b * 2 + tid] = s;
  }
}

// Zero-fill helper (avoid relying on memset semantics under graph capture)
__global__ __launch_bounds__(256)
void zero_fill(float* __restrict__ p, long n)
{
  long i = (long)blockIdx.x * 256 + threadIdx.x;
  if (i < n) p[i] = 0.f;
}

// ---------------------------------------------------------------------------
extern "C" void kernel_launch(void* const* d_in, const int* in_sizes, int n_in,
                              void* d_out, int out_size, void* d_ws, size_t ws_size,
                              hipStream_t stream)
{
  const float* x       = (const float*)d_in[0];
  const float* W_ih0   = (const float*)d_in[1];
  const float* W_hh0   = (const float*)d_in[2];
  const float* b_ih0   = (const float*)d_in[3];
  const float* b_hh0   = (const float*)d_in[4];
  const float* W_ih1   = (const float*)d_in[5];
  const float* W_hh1   = (const float*)d_in[6];
  const float* b_ih1   = (const float*)d_in[7];
  const float* b_hh1   = (const float*)d_in[8];
  const float* centers = (const float*)d_in[9];
  const float* eW1     = (const float*)d_in[10];
  const float* eb1     = (const float*)d_in[11];
  const float* eW2     = (const float*)d_in[12];
  const float* eb2     = (const float*)d_in[13];
  const float* eW3     = (const float*)d_in[14];
  const float* eb3     = (const float*)d_in[15];
  float* out = (float*)d_out;
  (void)in_sizes; (void)n_in; (void)out_size;

  // ---- workspace layout ----
  char* base = (char*)d_ws;
  size_t off = 0;
  auto alloc = [&](size_t nbytes) -> void* {
    void* p = base + off;
    off += (nbytes + 255) & ~(size_t)255;
    return p;
  };
  float* h0_state = (float*)alloc(1024ull * 256 * 4);
  float* h1_state = (float*)alloc(1024ull * 256 * 4);   // == z after layer 1
  float* qbuf     = (float*)alloc(1024ull * 8 * 4);
  float* h1buf    = (float*)alloc(1024ull * 8 * 512 * 4);
  float* h2buf    = (float*)alloc(1024ull * 8 * 256 * 4);
  float4* Wt0     = (float4*)alloc(768ull * 256 * 4);   // transposed W_hh0
  float4* Wt1     = (float4*)alloc(768ull * 256 * 4);   // transposed W_hh1
  const size_t fixed = off;

  // largest T-chunk that fits ws_size (deterministic given ws_size)
  int Tc = 2;
  const int cands[7] = {128, 64, 32, 16, 8, 4, 2};
  for (int ci = 0; ci < 7; ++ci) {
    size_t need = fixed + (size_t)cands[ci] * 1024 * (768 + 768 + 256) * 4 + 1024;
    if (need <= ws_size) { Tc = cands[ci]; break; }
  }
  float* gi0 = (float*)alloc((size_t)Tc * 1024 * 768 * 4);
  float* gi1 = (float*)alloc((size_t)Tc * 1024 * 768 * 4);
  float* h0c = (float*)alloc((size_t)Tc * 1024 * 256 * 4);

  // ---- zero recurrent states; transpose W_hh (once per call) ----
  {
    long n = 2L * 1024 * 256;   // h0_state + h1_state are contiguous
    zero_fill<<<dim3((unsigned)((n + 255) / 256)), 256, 0, stream>>>(h0_state, n);
    transpose_whh<<<768, 64, 0, stream>>>(W_hh0, Wt0);
    transpose_whh<<<768, 64, 0, stream>>>(W_hh1, Wt1);
  }

  // ---- 2-layer GRU, chunked over time ----
  for (int t0 = 0; t0 < 128; t0 += Tc) {
    // gi0[tl,b,:] = x[b, t0+tl, :] @ W_ih0^T + b_ih0
    gemm_f32<0><<<dim3(6, Tc * 8, 1), 256, 0, stream>>>(
        x + (long)t0 * 128, W_ih0, b_ih0, gi0, 128,
        /*a_sT*/ 128, /*a_sB*/ 128L * 128, /*a_sZ*/ 0,
        /*w_sZ*/ 0, /*b_sZ*/ 0, /*c_row*/ 768, /*c_sZ*/ 0);
    gru_rec<<<256, 1024, 0, stream>>>(gi0, Wt0, b_hh0, h0_state, h0c, Tc, 1);

    // gi1[tl,b,:] = h0c[tl,b,:] @ W_ih1^T + b_ih1
    gemm_f32<0><<<dim3(6, Tc * 8, 1), 256, 0, stream>>>(
        h0c, W_ih1, b_ih1, gi1, 256,
        /*a_sT*/ 1024L * 256, /*a_sB*/ 256, /*a_sZ*/ 0,
        /*w_sZ*/ 0, /*b_sZ*/ 0, /*c_row*/ 768, /*c_sZ*/ 0);
    gru_rec<<<256, 1024, 0, stream>>>(gi1, Wt1, b_hh1, h1_state, nullptr, Tc, 0);
  }

  // ---- soft cluster assignment ----
  cluster_q<<<1024, 64, 0, stream>>>(h1_state, centers, qbuf);

  // ---- experts: h1 = relu(z @ eW1[k]^T + eb1[k]) ----
  gemm_f32<1><<<dim3(4, 8, 8), 256, 0, stream>>>(
      h1_state, eW1, eb1, h1buf, 256,
      /*a_sT*/ 0, /*a_sB*/ 256, /*a_sZ*/ 0,
      /*w_sZ*/ 512L * 256, /*b_sZ*/ 512, /*c_row*/ 8L * 512, /*c_sZ*/ 512);
  // h2 = relu(h1 @ eW2[k]^T + eb2[k])
  gemm_f32<1><<<dim3(2, 8, 8), 256, 0, stream>>>(
      h1buf, eW2, eb2, h2buf, 512,
      /*a_sT*/ 0, /*a_sB*/ 8L * 512, /*a_sZ*/ 512,
      /*w_sZ*/ 256L * 512, /*b_sZ*/ 256, /*c_row*/ 8L * 256, /*c_sZ*/ 256);

  // ---- logits + q-weighted combine ----
  combine_preds<<<1024, 256, 0, stream>>>(h2buf, eW3, eb3, qbuf, out);
}